// Round 9
// baseline (32.830 us; speedup 1.0000x reference)
//
#include <hip/hip_runtime.h>
#include <math.h>

#define TROWS 16
#define FFEAT 129
#define DD    64
#define TILE  64          // batches per block in MLP kernel (16 per wave)
#define LROW  72          // fused-fallback LDS row pitch (ushorts)

typedef float f32x4 __attribute__((ext_vector_type(4)));
typedef short s16x8 __attribute__((ext_vector_type(8)));
typedef unsigned short u16x4 __attribute__((ext_vector_type(4)));

// x += dpp_mov(x, ctrl); invalid lanes contribute 0 (bound_ctrl=true).
#define DPP_ADD(x, ctrl)                                                     \
    (x) += __int_as_float(__builtin_amdgcn_update_dpp(                       \
        0, __float_as_int(x), (ctrl), 0xf, 0xf, true))

// 16-lane rotate-reduce (row_ror 8,4,2,1): ALL 16 lanes end with the row sum.
#define ROW_REDUCE(x)                                                        \
    do {                                                                     \
        DPP_ADD(x, 0x128); DPP_ADD(x, 0x124);                                \
        DPP_ADD(x, 0x122); DPP_ADD(x, 0x121);                                \
    } while (0)

__device__ __forceinline__ unsigned short f32_to_bf16(float f) {
    unsigned int u = __float_as_uint(f);
    return (unsigned short)((u + 0x7fffu + ((u >> 16) & 1u)) >> 16);
}

// slot s <-> column perm(s) = (s>>2) + 16*(s&3); shared by latent writer and
// B-fragment gather, so dot products are unaffected (k-perm invariance).
__device__ __forceinline__ int kperm(int s) {
    return (s >> 2) + ((s & 3) << 4);
}

// Load rows 13..15, cols {ll+16c}, of batch b: 12 coalesced scalar loads.
__device__ __forceinline__ void load12(float v[12], const float* __restrict__ fh,
                                       int b, int ll) {
    const float* base = fh + (size_t)b * (TROWS * FFEAT) + 13 * FFEAT + ll;
    #pragma unroll
    for (int r = 0; r < 3; ++r)
        #pragma unroll
        for (int c = 0; c < 4; ++c)
            v[r * 4 + c] = base[r * FFEAT + 16 * c];
}

// Stats phase: 16-lane group owns one batch; computes latest (bf16, kperm
// slot order) + dtw sim. Shared by kernel A and the fused fallback.
__device__ __forceinline__ void stats_one(const float v[12], int ll,
                                          u16x4* pk_out, float* sim_out) {
    float cl[12];
    #pragma unroll
    for (int j = 0; j < 12; ++j)
        cl[j] = fminf(fmaxf(fabsf(v[j]), 1e-5f), 10.0f);

    float s = 0.0f, sq = 0.0f, dd = 0.0f;
    #pragma unroll
    for (int j = 0; j < 12; ++j) { s += cl[j]; sq = fmaf(cl[j], cl[j], sq); }
    #pragma unroll
    for (int c = 0; c < 4; ++c) {
        const float d = v[c] - v[8 + c];     // RAW rows 13/15
        dd = fmaf(d, d, dd);
    }
    ROW_REDUCE(s); ROW_REDUCE(sq); ROW_REDUCE(dd);

    const float mean = s * (1.0f / 192.0f);
    float var = (sq - s * s * (1.0f / 192.0f)) * (1.0f / 191.0f);
    var = fmaxf(var, 0.0f);
    const float stdv = sqrtf(var) + 1e-5f;
    const float rinv = __fdividef(1.0f, stdv);

    u16x4 pk;
    #pragma unroll
    for (int c = 0; c < 4; ++c) {
        const float lat = fminf(fmaxf((cl[8 + c] - mean) * rinv, -3.0f), 3.0f);
        pk[c] = f32_to_bf16(lat);
    }
    *pk_out = pk;
    *sim_out = __expf(-sqrtf(dd) * (1.0f / 256.0f));
}

// ===================== Kernel A: stats / latest (8 waves/SIMD) =============
__global__ __launch_bounds__(256, 8) void stats_kernel(
    const float* __restrict__ fh,
    unsigned short* __restrict__ lat,
    float* __restrict__ out,
    int nB)
{
    const int tid  = threadIdx.x;
    const int lane = tid & 63;
    const int ll   = lane & 15;
    const int g    = lane >> 4;

    const int wid = (blockIdx.x * 256 + tid) >> 6;   // global wave id
    const int nW  = (gridDim.x * 256) >> 6;
    const int nTasks = nB >> 2;                      // 4 batches per task

    for (int task = wid; task < nTasks; task += nW) {
        const int b = task * 4 + g;
        float v[12];
        load12(v, fh, b, ll);

        u16x4 pk; float sim;
        stats_one(v, ll, &pk, &sim);

        *(u16x4*)&lat[(size_t)b * DD + ll * 4] = pk;
        if (ll == 0) out[nB + b] = sim;
    }
}

// ===================== Kernel B: MFMA + LN/GELU/W2 =========================
__global__ __launch_bounds__(256, 4) void mlp_kernel(
    const unsigned short* __restrict__ lat,
    const float* __restrict__ W1,
    const float* __restrict__ b1,
    const float* __restrict__ gamma,
    const float* __restrict__ beta,
    const float* __restrict__ W2,
    const float* __restrict__ b2,
    float* __restrict__ out,
    int nB)
{
    const int tid  = threadIdx.x;
    const int lane = tid & 63;
    const int wib  = tid >> 6;
    const int n0   = lane & 15;
    const int kg   = lane >> 4;

    // B fragments: W1 as bf16, gathered through kperm.
    s16x8 Bf[2][4];
    #pragma unroll
    for (int h = 0; h < 2; ++h) {
        #pragma unroll
        for (int t = 0; t < 4; ++t) {
            #pragma unroll
            for (int j = 0; j < 8; ++j) {
                const int s = h * 32 + kg * 8 + j;
                const float w = W1[kperm(s) * DD + (n0 + 16 * t)];
                Bf[h][t][j] = (short)f32_to_bf16(w);
            }
        }
    }
    float b1v[4], gv[4], bv[4], w2v[4];
    #pragma unroll
    for (int t = 0; t < 4; ++t) {
        const int nt = n0 + 16 * t;
        b1v[t] = b1[nt]; gv[t] = gamma[nt]; bv[t] = beta[nt]; w2v[t] = W2[nt];
    }
    const float b2s = b2[0];

    const int bbase = blockIdx.x * TILE;
    const int r = wib * 16 + n0;                 // A-row = batch within tile
    const unsigned short* ar = lat + (size_t)(bbase + r) * DD + kg * 8;
    const s16x8 a0 = *(const s16x8*)(ar);        // slots kg*8+j        (h=0)
    const s16x8 a1 = *(const s16x8*)(ar + 32);   // slots 32+kg*8+j     (h=1)

    f32x4 acc[4];
    #pragma unroll
    for (int t = 0; t < 4; ++t) {
        acc[t] = f32x4{0.0f, 0.0f, 0.0f, 0.0f};
        acc[t] = __builtin_amdgcn_mfma_f32_16x16x32_bf16(a0, Bf[0][t], acc[t], 0, 0, 0);
        acc[t] = __builtin_amdgcn_mfma_f32_16x16x32_bf16(a1, Bf[1][t], acc[t], 0, 0, 0);
    }

    // D layout: batch m = kg*4 + q (within M-tile), feature n = n0 + 16t.
    #pragma unroll
    for (int q = 0; q < 4; ++q) {
        const float h0 = acc[0][q] + b1v[0];
        const float h1 = acc[1][q] + b1v[1];
        const float h2 = acc[2][q] + b1v[2];
        const float h3 = acc[3][q] + b1v[3];

        float s  = (h0 + h1) + (h2 + h3);
        float ss = fmaf(h0, h0, fmaf(h1, h1, fmaf(h2, h2, h3 * h3)));
        ROW_REDUCE(s); ROW_REDUCE(ss);

        const float mu = s * (1.0f / 64.0f);
        float vv = ss * (1.0f / 64.0f) - mu * mu;
        vv = fmaxf(vv, 0.0f);
        const float rstd = rsqrtf(vv + 1e-5f);

        float sc = 0.0f;
        #pragma unroll
        for (int t = 0; t < 4; ++t) {
            const float hv = (t == 0) ? h0 : (t == 1) ? h1 : (t == 2) ? h2 : h3;
            const float hn = (hv - mu) * rstd * gv[t] + bv[t];
            const float y  = 0.7978845608028654f *
                             fmaf(0.044715f * hn * hn, hn, hn);
            const float ey = __expf(2.0f * y);
            const float th = 1.0f - __fdividef(2.0f, ey + 1.0f);
            const float ge = 0.5f * hn * (1.0f + th);
            sc = fmaf(ge, w2v[t], sc);
        }
        ROW_REDUCE(sc);

        const float rep = __fdividef(1.0f, 1.0f + __expf(-(sc + b2s)));
        if (n0 == q) out[bbase + wib * 16 + kg * 4 + q] = rep;
    }
}

// ===================== Fused fallback (R7, proven) =========================
__global__ __launch_bounds__(256, 4) void fused_kernel(
    const float* __restrict__ fh,
    const float* __restrict__ W1,
    const float* __restrict__ b1,
    const float* __restrict__ gamma,
    const float* __restrict__ beta,
    const float* __restrict__ W2,
    const float* __restrict__ b2,
    float* __restrict__ out,
    int nB)
{
    __shared__ unsigned short sLat[TILE * LROW];

    const int tid  = threadIdx.x;
    const int lane = tid & 63;
    const int wib  = tid >> 6;
    const int n0   = lane & 15;
    const int kg   = lane >> 4;

    s16x8 Bf[2][4];
    #pragma unroll
    for (int h = 0; h < 2; ++h)
        #pragma unroll
        for (int t = 0; t < 4; ++t)
            #pragma unroll
            for (int j = 0; j < 8; ++j) {
                const int s = h * 32 + kg * 8 + j;
                Bf[h][t][j] = (short)f32_to_bf16(W1[kperm(s) * DD + (n0 + 16 * t)]);
            }
    float b1v[4], gv[4], bv[4], w2v[4];
    #pragma unroll
    for (int t = 0; t < 4; ++t) {
        const int nt = n0 + 16 * t;
        b1v[t] = b1[nt]; gv[t] = gamma[nt]; bv[t] = beta[nt]; w2v[t] = W2[nt];
    }
    const float b2s = b2[0];

    const int bbase = blockIdx.x * TILE;
    const int wb    = bbase + wib * 16;
    const int ll    = n0;
    const int g     = kg;

    float cur[12], nxt[12];
    load12(cur, fh, wb + g, ll);

    #pragma unroll
    for (int i = 0; i < 4; ++i) {
        if (i < 3) load12(nxt, fh, wb + 4 * (i + 1) + g, ll);
        u16x4 pk; float sim;
        stats_one(cur, ll, &pk, &sim);
        const int row = wib * 16 + 4 * i + g;
        *(u16x4*)&sLat[row * LROW + ll * 4] = pk;
        if (ll == 0) out[nB + (wb + 4 * i + g)] = sim;
        #pragma unroll
        for (int j = 0; j < 12; ++j) cur[j] = nxt[j];
    }

    const int r = wib * 16 + n0;
    const unsigned short* ar = &sLat[r * LROW + kg * 8];
    const s16x8 a0 = *(const s16x8*)(ar);
    const s16x8 a1 = *(const s16x8*)(ar + 32);

    f32x4 acc[4];
    #pragma unroll
    for (int t = 0; t < 4; ++t) {
        acc[t] = f32x4{0.0f, 0.0f, 0.0f, 0.0f};
        acc[t] = __builtin_amdgcn_mfma_f32_16x16x32_bf16(a0, Bf[0][t], acc[t], 0, 0, 0);
        acc[t] = __builtin_amdgcn_mfma_f32_16x16x32_bf16(a1, Bf[1][t], acc[t], 0, 0, 0);
    }
    #pragma unroll
    for (int q = 0; q < 4; ++q) {
        const float h0 = acc[0][q] + b1v[0];
        const float h1 = acc[1][q] + b1v[1];
        const float h2 = acc[2][q] + b1v[2];
        const float h3 = acc[3][q] + b1v[3];
        float s  = (h0 + h1) + (h2 + h3);
        float ss = fmaf(h0, h0, fmaf(h1, h1, fmaf(h2, h2, h3 * h3)));
        ROW_REDUCE(s); ROW_REDUCE(ss);
        const float mu = s * (1.0f / 64.0f);
        float vv = ss * (1.0f / 64.0f) - mu * mu;
        vv = fmaxf(vv, 0.0f);
        const float rstd = rsqrtf(vv + 1e-5f);
        float sc = 0.0f;
        #pragma unroll
        for (int t = 0; t < 4; ++t) {
            const float hv = (t == 0) ? h0 : (t == 1) ? h1 : (t == 2) ? h2 : h3;
            const float hn = (hv - mu) * rstd * gv[t] + bv[t];
            const float y  = 0.7978845608028654f * fmaf(0.044715f * hn * hn, hn, hn);
            const float ey = __expf(2.0f * y);
            const float th = 1.0f - __fdividef(2.0f, ey + 1.0f);
            sc = fmaf(0.5f * hn * (1.0f + th), w2v[t], sc);
        }
        ROW_REDUCE(sc);
        const float rep = __fdividef(1.0f, 1.0f + __expf(-(sc + b2s)));
        if (n0 == q) out[bbase + wib * 16 + kg * 4 + q] = rep;
    }
}

extern "C" void kernel_launch(void* const* d_in, const int* in_sizes, int n_in,
                              void* d_out, int out_size, void* d_ws, size_t ws_size,
                              hipStream_t stream) {
    const float* fh    = (const float*)d_in[0];
    const float* W1    = (const float*)d_in[1];
    const float* b1    = (const float*)d_in[2];
    const float* gamma = (const float*)d_in[3];
    const float* beta  = (const float*)d_in[4];
    const float* W2    = (const float*)d_in[5];
    const float* b2    = (const float*)d_in[6];
    float* out = (float*)d_out;

    const int nB = in_sizes[0] / (TROWS * FFEAT);   // 65536
    const size_t latBytes = (size_t)nB * DD * sizeof(unsigned short);  // 8 MB

    if (ws_size >= latBytes) {
        unsigned short* lat = (unsigned short*)d_ws;
        // A: 2048 blocks x 4 waves @ 8 waves/SIMD; 2 tasks/wave.
        stats_kernel<<<2048, 256, 0, stream>>>(fh, lat, out, nB);
        // B: one 64-batch tile per block.
        mlp_kernel<<<nB / TILE, 256, 0, stream>>>(lat, W1, b1, gamma, beta,
                                                  W2, b2, out, nB);
    } else {
        fused_kernel<<<nB / TILE, 256, 0, stream>>>(fh, W1, b1, gamma, beta,
                                                    W2, b2, out, nB);
    }
}

// Round 10
// 24.845 us; speedup vs baseline: 1.3214x; 1.3214x over previous
//
#include <hip/hip_runtime.h>
#include <math.h>

#define TROWS 16
#define FFEAT 129
#define DD    64
#define TILE  64          // batches per block (16 per wave)
#define LROW  72          // ushort elems per LDS latent row (144 B)

typedef float f32x4 __attribute__((ext_vector_type(4)));
typedef short s16x8 __attribute__((ext_vector_type(8)));
typedef unsigned short u16x4 __attribute__((ext_vector_type(4)));

// x += dpp_mov(x, ctrl); invalid lanes contribute 0 (bound_ctrl=true).
#define DPP_ADD(x, ctrl)                                                     \
    (x) += __int_as_float(__builtin_amdgcn_update_dpp(                       \
        0, __float_as_int(x), (ctrl), 0xf, 0xf, true))

// 16-lane rotate-reduce (row_ror 8,4,2,1): ALL 16 lanes end with the row sum.
#define ROW_REDUCE(x)                                                        \
    do {                                                                     \
        DPP_ADD(x, 0x128); DPP_ADD(x, 0x124);                                \
        DPP_ADD(x, 0x122); DPP_ADD(x, 0x121);                                \
    } while (0)

__device__ __forceinline__ unsigned short f32_to_bf16(float f) {
    unsigned int u = __float_as_uint(f);
    return (unsigned short)((u + 0x7fffu + ((u >> 16) & 1u)) >> 16);
}

// k-slot permutation shared by A and B fragments: slot s <-> column
// perm(s) = (s>>2) + 16*(s&3). Dot products are k-permutation invariant.
__device__ __forceinline__ int kperm(int s) {
    return (s >> 2) + ((s & 3) << 4);
}

// Load rows 13..15, cols {ll+16c}, of batch b: 12 coalesced scalar loads.
__device__ __forceinline__ void load12(float v[12], const float* __restrict__ fh,
                                       int b, int ll) {
    const float* base = fh + (size_t)b * (TROWS * FFEAT) + 13 * FFEAT + ll;
    #pragma unroll
    for (int r = 0; r < 3; ++r)
        #pragma unroll
        for (int c = 0; c < 4; ++c)
            v[r * 4 + c] = base[r * FFEAT + 16 * c];
}

__global__ __launch_bounds__(256, 4) void dtw_tracker_kernel(
    const float* __restrict__ fh,
    const float* __restrict__ W1,
    const float* __restrict__ b1,
    const float* __restrict__ gamma,
    const float* __restrict__ beta,
    const float* __restrict__ W2,
    const float* __restrict__ b2,
    float* __restrict__ out,
    int nB)
{
    __shared__ unsigned short sLat[TILE * LROW];   // 9216 B

    const int tid  = threadIdx.x;
    const int lane = tid & 63;
    const int wib  = tid >> 6;
    const int n0   = lane & 15;     // A: lane-in-group; B: n-col / A-row
    const int kg   = lane >> 4;     // A: group (batch); B: k-group

    // ---- B fragments: W1 as bf16, gathered through kperm ----
    s16x8 Bf[2][4];
    #pragma unroll
    for (int h = 0; h < 2; ++h) {
        #pragma unroll
        for (int t = 0; t < 4; ++t) {
            #pragma unroll
            for (int j = 0; j < 8; ++j) {
                const int s = h * 32 + kg * 8 + j;
                const float w = W1[kperm(s) * DD + (n0 + 16 * t)];
                Bf[h][t][j] = (short)f32_to_bf16(w);
            }
        }
    }

    // Per-lane epilogue constants (feature n = n0 + 16t).
    float b1v[4], gv[4], bv[4], w2v[4];
    #pragma unroll
    for (int t = 0; t < 4; ++t) {
        const int nt = n0 + 16 * t;
        b1v[t] = b1[nt]; gv[t] = gamma[nt]; bv[t] = beta[nt]; w2v[t] = W2[nt];
    }
    const float b2s = b2[0];

    // =========== Phase A: 4 iterations, 4 batches each (16-lane groups) ====
    const int bbase = blockIdx.x * TILE;
    const int wb    = bbase + wib * 16;          // wave's first batch
    const int ll    = n0;
    const int g     = kg;

    float cur[12], nxt[12];
    load12(cur, fh, wb + g, ll);

    #pragma unroll
    for (int i = 0; i < 4; ++i) {
        if (i < 3) load12(nxt, fh, wb + 4 * (i + 1) + g, ll);

        // clipped magnitudes
        float cl[12];
        #pragma unroll
        for (int j = 0; j < 12; ++j)
            cl[j] = fminf(fmaxf(fabsf(cur[j]), 1e-5f), 10.0f);

        // per-lane partials: sum, sumsq over 12; dist over row13-row15 (RAW)
        float s = 0.0f, sq = 0.0f, dd = 0.0f;
        #pragma unroll
        for (int j = 0; j < 12; ++j) { s += cl[j]; sq = fmaf(cl[j], cl[j], sq); }
        #pragma unroll
        for (int c = 0; c < 4; ++c) {
            const float d = cur[c] - cur[8 + c];
            dd = fmaf(d, d, dd);
        }
        // three independent 4-step reduces over the 16-lane group
        ROW_REDUCE(s); ROW_REDUCE(sq); ROW_REDUCE(dd);

        const float mean = s * (1.0f / 192.0f);
        float var = (sq - s * s * (1.0f / 192.0f)) * (1.0f / 191.0f);
        var = fmaxf(var, 0.0f);
        const float stdv = sqrtf(var) + 1e-5f;
        const float rinv = __fdividef(1.0f, stdv);

        // latest cols {ll+16c} -> LDS slots ll*4+c (kperm order), one b64 write
        u16x4 pk;
        #pragma unroll
        for (int c = 0; c < 4; ++c) {
            const float lat =
                fminf(fmaxf((cl[8 + c] - mean) * rinv, -3.0f), 3.0f);
            pk[c] = f32_to_bf16(lat);
        }
        const int row = wib * 16 + 4 * i + g;
        *(u16x4*)&sLat[row * LROW + ll * 4] = pk;

        if (ll == 0)
            out[nB + (wb + 4 * i + g)] = __expf(-sqrtf(dd) * (1.0f / 256.0f));

        #pragma unroll
        for (int j = 0; j < 12; ++j) cur[j] = nxt[j];
    }
    // No barrier: each wave reads back only the LDS rows it wrote.

    // =========== Phase B: 16x64 @ 64x64 via MFMA, then LN/GELU/W2 ==========
    const int r = wib * 16 + n0;                 // A-row = batch within tile
    const unsigned short* ar = &sLat[r * LROW + kg * 8];
    const s16x8 a0 = *(const s16x8*)(ar);        // slots kg*8+j        (h=0)
    const s16x8 a1 = *(const s16x8*)(ar + 32);   // slots 32+kg*8+j     (h=1)

    f32x4 acc[4];
    #pragma unroll
    for (int t = 0; t < 4; ++t) {
        acc[t] = f32x4{0.0f, 0.0f, 0.0f, 0.0f};
        acc[t] = __builtin_amdgcn_mfma_f32_16x16x32_bf16(a0, Bf[0][t], acc[t], 0, 0, 0);
        acc[t] = __builtin_amdgcn_mfma_f32_16x16x32_bf16(a1, Bf[1][t], acc[t], 0, 0, 0);
    }

    // D layout: batch m = kg*4 + q (within M-tile), feature n = n0 + 16t.
    #pragma unroll
    for (int q = 0; q < 4; ++q) {
        const float h0 = acc[0][q] + b1v[0];
        const float h1 = acc[1][q] + b1v[1];
        const float h2 = acc[2][q] + b1v[2];
        const float h3 = acc[3][q] + b1v[3];

        float s  = (h0 + h1) + (h2 + h3);
        float ss = fmaf(h0, h0, fmaf(h1, h1, fmaf(h2, h2, h3 * h3)));
        ROW_REDUCE(s); ROW_REDUCE(ss);           // sums over the 64 features

        const float mu = s * (1.0f / 64.0f);
        float vv = ss * (1.0f / 64.0f) - mu * mu;
        vv = fmaxf(vv, 0.0f);
        const float rstd = rsqrtf(vv + 1e-5f);

        float sc = 0.0f;
        #pragma unroll
        for (int t = 0; t < 4; ++t) {
            const float hv = (t == 0) ? h0 : (t == 1) ? h1 : (t == 2) ? h2 : h3;
            const float hn = (hv - mu) * rstd * gv[t] + bv[t];
            const float y  = 0.7978845608028654f *
                             fmaf(0.044715f * hn * hn, hn, hn);
            const float ey = __expf(2.0f * y);
            const float th = 1.0f - __fdividef(2.0f, ey + 1.0f);
            const float ge = 0.5f * hn * (1.0f + th);
            sc = fmaf(ge, w2v[t], sc);
        }
        ROW_REDUCE(sc);

        const float rep = __fdividef(1.0f, 1.0f + __expf(-(sc + b2s)));
        if (n0 == q) {
            const int bidx = bbase + wib * 16 + kg * 4 + q;
            out[bidx] = rep;
        }
    }
}

extern "C" void kernel_launch(void* const* d_in, const int* in_sizes, int n_in,
                              void* d_out, int out_size, void* d_ws, size_t ws_size,
                              hipStream_t stream) {
    const float* fh    = (const float*)d_in[0];
    const float* W1    = (const float*)d_in[1];
    const float* b1    = (const float*)d_in[2];
    const float* gamma = (const float*)d_in[3];
    const float* beta  = (const float*)d_in[4];
    const float* W2    = (const float*)d_in[5];
    const float* b2    = (const float*)d_in[6];
    float* out = (float*)d_out;

    const int nB = in_sizes[0] / (TROWS * FFEAT);   // 65536

    // One 64-batch tile per block: 1024 blocks = 4/CU, single round, no tail.
    const int nBlocks = nB / TILE;
    dtw_tracker_kernel<<<nBlocks, 256, 0, stream>>>(fh, W1, b1, gamma, beta,
                                                    W2, b2, out, nB);
}